// Round 6
// baseline (359.841 us; speedup 1.0000x reference)
//
#include <hip/hip_runtime.h>
#include <stdint.h>

typedef unsigned short u16;
typedef unsigned int u32;
typedef __attribute__((ext_vector_type(8))) short short8;
typedef __attribute__((ext_vector_type(4))) float f32x4;

#define NHEADS 16
#define SEQ 2048
#define DM 1024
#define MROWS 4096 // B*S
#define FF 4096

static_assert(sizeof(short8) == 16, "short8 must be 16B");

// ---------- helpers ----------
__device__ __forceinline__ u16 f2b(float f) {
  u32 u = __float_as_uint(f);
  u += 0x7fffu + ((u >> 16) & 1u); // RNE
  return (u16)(u >> 16);
}
__device__ __forceinline__ u32 f2b2(float lo, float hi) {
  u32 a = __float_as_uint(lo); a += 0x7fffu + ((a >> 16) & 1u);
  u32 b = __float_as_uint(hi); b += 0x7fffu + ((b >> 16) & 1u);
  return (a >> 16) | (b & 0xffff0000u);
}
// truncating pack (1 v_perm_b32): [lo.hi16 | hi.hi16]
__device__ __forceinline__ u32 f2b2t(float lo, float hi) {
  return __builtin_amdgcn_perm(__float_as_uint(hi), __float_as_uint(lo), 0x07060302u);
}
__device__ __forceinline__ float b2f(u16 h) { return __uint_as_float(((u32)h) << 16); }

__device__ __forceinline__ void async_cp16(const u16* g, u16* l) {
  __builtin_amdgcn_global_load_lds((const __attribute__((address_space(1))) void*)g,
                                   (__attribute__((address_space(3))) void*)l, 16, 0, 0);
}

// ---------- fused prep: cvt x -> bf16, transpose all weights -> bf16 [N,K] ----------
__global__ __launch_bounds__(256) void prep_k(const float* __restrict__ x,
                                              const float* __restrict__ wq,
                                              const float* __restrict__ wk,
                                              const float* __restrict__ wv,
                                              const float* __restrict__ wo,
                                              const float* __restrict__ w1,
                                              const float* __restrict__ w2,
                                              u16* __restrict__ xb, u16* __restrict__ btq,
                                              u16* __restrict__ wot, u16* __restrict__ w1t,
                                              u16* __restrict__ w2t) {
  const int bid = blockIdx.x, tid = threadIdx.x;
  if (bid < 4096) { // cvt x (4M floats, 1 float4/thread)
    const int i = bid * 256 + tid;
    const float4 v = ((const float4*)x)[i];
    uint2 o; o.x = f2b2(v.x, v.y); o.y = f2b2(v.z, v.w);
    ((uint2*)xb)[i] = o;
    return;
  }
  __shared__ float tile[32][33];
  const int tb = bid - 4096;
  const float* in; u16* out; int N, K, n0, k0;
  if (tb < 4096) {
    const int m = tb >> 10, t = tb & 1023;
    if (m == 0) { in = wq; out = btq; }
    else if (m == 1) { in = wk; out = btq + 1024 * 1024; }
    else if (m == 2) { in = wv; out = btq + 2 * 1024 * 1024; }
    else { in = wo; out = wot; }
    N = 1024; K = 1024; n0 = (t & 31) * 32; k0 = (t >> 5) * 32;
  } else if (tb < 8192) {
    const int t = tb - 4096;
    in = w1; out = w1t; N = 4096; K = 1024; n0 = (t & 127) * 32; k0 = (t >> 7) * 32;
  } else {
    const int t = tb - 8192;
    in = w2; out = w2t; N = 1024; K = 4096; n0 = (t & 31) * 32; k0 = (t >> 5) * 32;
  }
  const int tx = tid & 31, ty = tid >> 5;
#pragma unroll
  for (int i = 0; i < 4; i++) {
    const int r = ty + i * 8;
    tile[r][tx] = in[(long)(k0 + r) * N + n0 + tx];
  }
  __syncthreads();
#pragma unroll
  for (int i = 0; i < 4; i++) {
    const int r = ty + i * 8;
    out[(long)(n0 + r) * K + k0 + tx] = f2b(tile[tx][r]);
  }
}

// ---------- GEMM C = A @ Bt^T  (A:[M,K] bf16, Bt:[N,K] bf16) ----------
#define BM 128
#define BN 128
#define BK 64
#define EPI_QKV 0
#define EPI_ADDRES 1
#define EPI_RELUB 2

template <int EPI>
__global__ __launch_bounds__(256, 2) void gemm_bt(
    const u16* __restrict__ A, const u16* __restrict__ Bt, const int M, const int N,
    const int K, const float* __restrict__ bias0, const float* __restrict__ bias1,
    const float* __restrict__ bias2, const float* __restrict__ resid,
    float* __restrict__ outF, u16* __restrict__ outB, u16* __restrict__ outQ,
    u16* __restrict__ outK, u16* __restrict__ outV) {
  __shared__ u16 As[BM * BK];
  __shared__ u16 Bs[BN * BK];
  const int tid = threadIdx.x;
  const int lane = tid & 63;
  const int wv = tid >> 6;
  const int quad = lane >> 4;
  const int lm = lane & 15;
  const int tn = blockIdx.x * BN;
  const int tm = blockIdx.y * BM;
  const int wr = (wv >> 1) * 64;
  const int wc = (wv & 1) * 64;
  const int wslotbase = tid & ~63;

  const f32x4 z4 = {0.f, 0.f, 0.f, 0.f};
  f32x4 acc[4][4];
#pragma unroll
  for (int i = 0; i < 4; i++)
#pragma unroll
    for (int j = 0; j < 4; j++) acc[i][j] = z4;

  for (int kk = 0; kk < K; kk += BK) {
    __syncthreads();
#pragma unroll
    for (int t = 0; t < 4; t++) {
      const int slot = t * 256 + tid;
      const int row = slot >> 3;
      const int c = (slot & 7) ^ (row & 7);
      async_cp16(A + (long)(tm + row) * K + kk + c * 8,
                 As + (long)(t * 256 + wslotbase) * 8);
    }
#pragma unroll
    for (int t = 0; t < 4; t++) {
      const int slot = t * 256 + tid;
      const int row = slot >> 3;
      const int c = (slot & 7) ^ (row & 7);
      async_cp16(Bt + (long)(tn + row) * K + kk + c * 8,
                 Bs + (long)(t * 256 + wslotbase) * 8);
    }
    __syncthreads();
#pragma unroll
    for (int ks = 0; ks < 2; ks++) {
      short8 af[4], bf[4];
#pragma unroll
      for (int mi = 0; mi < 4; mi++) {
        const int row = wr + mi * 16 + lm;
        const int cc = (4 * ks + quad) ^ (row & 7);
        af[mi] = *(const short8*)(As + row * 64 + cc * 8);
      }
#pragma unroll
      for (int ni = 0; ni < 4; ni++) {
        const int row = wc + ni * 16 + lm;
        const int cc = (4 * ks + quad) ^ (row & 7);
        bf[ni] = *(const short8*)(Bs + row * 64 + cc * 8);
      }
#pragma unroll
      for (int mi = 0; mi < 4; mi++)
#pragma unroll
        for (int ni = 0; ni < 4; ni++)
          acc[mi][ni] =
              __builtin_amdgcn_mfma_f32_16x16x32_bf16(af[mi], bf[ni], acc[mi][ni], 0, 0, 0);
    }
  }

  if constexpr (EPI == EPI_QKV) {
    const int which = tn >> 10; // 0=q,1=k,2=v (block-uniform)
    const int bb = tm >> 11;
    if (which < 2) {
      const float* bs = which == 0 ? bias0 : bias1;
      u16* os = which == 0 ? outQ : outK;
      // q pre-scale: 1/sqrt(64) * log2(e) folded in -> attn uses exp2 directly
      const float scale = which == 0 ? 0.125f * 1.44269504f : 1.0f;
#pragma unroll
      for (int ni = 0; ni < 4; ni++) {
        const int n = tn + wc + ni * 16 + lm;
        const int hd = n & 1023;
        const int h = hd >> 6, dep = hd & 63;
        const float bval = bs[hd];
#pragma unroll
        for (int mi = 0; mi < 4; mi++) {
#pragma unroll
          for (int r = 0; r < 4; r++) {
            const int ss = (tm & 2047) + wr + mi * 16 + quad * 4 + r;
            os[(((long)(bb * NHEADS + h) * SEQ + ss) << 6) + dep] =
                f2b((acc[mi][ni][r] + bval) * scale);
          }
        }
      }
    } else { // V: write transposed [B,H,64,S] directly (8B stores per lane)
#pragma unroll
      for (int ni = 0; ni < 4; ni++) {
        const int n = tn + wc + ni * 16 + lm;
        const int hd = n & 1023;
        const int h = hd >> 6, dep = hd & 63;
        const float bval = bias2[hd];
        u16* vrow = outV + ((long)(bb * NHEADS + h) * 64 + dep) * SEQ;
#pragma unroll
        for (int mi = 0; mi < 4; mi++) {
          const int ss = (tm & 2047) + wr + mi * 16 + quad * 4;
          uint2 o;
          o.x = f2b2(acc[mi][ni][0] + bval, acc[mi][ni][1] + bval);
          o.y = f2b2(acc[mi][ni][2] + bval, acc[mi][ni][3] + bval);
          *(uint2*)(vrow + ss) = o;
        }
      }
    }
  } else {
#pragma unroll
    for (int mi = 0; mi < 4; mi++) {
#pragma unroll
      for (int r = 0; r < 4; r++) {
        const int m = tm + wr + mi * 16 + quad * 4 + r;
        const long rowo = (long)m * N;
#pragma unroll
        for (int ni = 0; ni < 4; ni++) {
          const int n = tn + wc + ni * 16 + lm;
          const float v = acc[mi][ni][r] + bias0[n];
          if constexpr (EPI == EPI_ADDRES) {
            outF[rowo + n] = v + resid[rowo + n]; // fused bias + residual, fp32
          } else {
            outB[rowo + n] = f2b(fmaxf(v, 0.f)); // fused bias + ReLU, bf16
          }
        }
      }
    }
  }
}

// ---------- fused causal attention, k-split with exact-softmax partials ----------
// Q,K: [B,H,S,64] bf16 (q pre-scaled by 0.125*log2e); Vt: [B,H,64,S]; O: [B,S,DM].
// No online max (scores bounded, exp2 exact) => flash partials combine by PLAIN
// SUMMATION. Block = 256 thr / 4 waves / one 64-row q-tile; wave owns 16 rows.
// qt < 16: single block, full k-range, final bf16. qt >= 16: two blocks, half
// k-range each, fp32 ctx partial + l; combine kernel sums. P packed to bf16 via
// v_perm (truncation). K/V double-buffered; staging geometry hoisted.
__global__ __launch_bounds__(256, 3) void attn_fused(const u16* __restrict__ Q,
                                                     const u16* __restrict__ K,
                                                     const u16* __restrict__ Vt,
                                                     u16* __restrict__ O,
                                                     float* __restrict__ part,
                                                     float* __restrict__ lpart) {
  __shared__ u16 Ks[2][64 * 64];
  __shared__ u16 Vs[2][64 * 64];
  __shared__ u16 Ps[4][16 * 72];
  const int tid = threadIdx.x;
  const int lane = tid & 63, w = tid >> 6, quad = lane >> 4, lm = lane & 15;
  const int bid = blockIdx.x;
  const int idx = bid >> 5, hb = bid & 31;
  const int h = hb & 15, b = hb >> 4;
  int qt, c0, nkl, half;
  if (idx < 32) { // halves of qt 16..31 (dispatched first: longest work)
    qt = 16 + (idx >> 1);
    const int nk = qt + 1;
    const int h0 = (nk + 1) >> 1;
    half = idx & 1;
    if (half == 0) { c0 = 0; nkl = h0; } else { c0 = h0; nkl = nk - h0; }
  } else { // singles qt 15..0
    qt = 47 - idx; c0 = 0; nkl = qt + 1; half = -1;
  }
  const long bh = (long)(b * NHEADS + h);
  const u16* Qb = Q + bh * SEQ * 64;
  const u16* Kb = K + bh * SEQ * 64;
  const u16* Vb = Vt + bh * (long)64 * SEQ;
  const int rbase = qt * 64 + w * 16; // wave's 16 q-rows
  const int wslot = tid & ~63;

  // hoisted per-thread staging geometry (2 16B slots per thread per buffer)
  long kgo[2], vgo[2];
  int ldso[2];
#pragma unroll
  for (int i = 0; i < 2; i++) {
    const int slot = i * 256 + tid;
    const int row = slot >> 3;
    const int cg = (slot & 7) ^ (row & 7);
    kgo[i] = (long)row * 64 + cg * 8;
    vgo[i] = (long)row * SEQ + cg * 8;
    ldso[i] = (i * 256 + wslot) * 8;
  }

  // Q frag (B-operand): lane holds Q[rbase+lm][ks*32+quad*8 ..+7]
  short8 qf[2];
#pragma unroll
  for (int ks = 0; ks < 2; ks++)
    qf[ks] = *(const short8*)(Qb + (long)(rbase + lm) * 64 + ks * 32 + quad * 8);

  const f32x4 z4 = {0.f, 0.f, 0.f, 0.f};
  f32x4 ctx[4];
#pragma unroll
  for (int d = 0; d < 4; d++) ctx[d] = z4;
  float lacc = 0.f;
  u16* myP = (u16*)Ps[w];

  { // prologue: stage tile c0 into buffer 0
    const long ko = (long)c0 * 64 * 64;
#pragma unroll
    for (int i = 0; i < 2; i++) {
      async_cp16(Kb + ko + kgo[i], Ks[0] + ldso[i]);
      async_cp16(Vb + c0 * 64 + vgo[i], Vs[0] + ldso[i]);
    }
  }

  for (int t = 0; t < nkl; t++) {
    const int cur = t & 1;
    const int k0 = (c0 + t) * 64;
    __syncthreads(); // buf[cur] DMA drained (prefetched a full phase ago)
    if (t + 1 < nkl) {
      const long ko = (long)(k0 + 64) * 64;
#pragma unroll
      for (int i = 0; i < 2; i++) {
        async_cp16(Kb + ko + kgo[i], Ks[1 - cur] + ldso[i]);
        async_cp16(Vb + (k0 + 64) + vgo[i], Vs[1 - cur] + ldso[i]);
      }
    }
    const u16* Kc = Ks[cur];
    const u16* Vc = Vs[cur];
    short8 kf[4][2]; // A-operand: K[k0+ni*16+lm][ks*32+quad*8 ..+7]
#pragma unroll
    for (int ni = 0; ni < 4; ni++) {
      const int row = ni * 16 + lm;
      const int r8 = row & 7;
#pragma unroll
      for (int ks = 0; ks < 2; ks++) {
        const int cc = (ks * 4 + quad) ^ r8;
        kf[ni][ks] = *(const short8*)(Kc + row * 64 + cc * 8);
      }
    }
    f32x4 sa[4]; // S^T: lane holds key=k0+ni*16+quad*4+r, qrow=rbase+lm
#pragma unroll
    for (int i = 0; i < 4; i++) sa[i] = z4;
#pragma unroll
    for (int ks = 0; ks < 2; ks++)
#pragma unroll
      for (int ni = 0; ni < 4; ni++)
        sa[ni] = __builtin_amdgcn_mfma_f32_16x16x32_bf16(kf[ni][ks], qf[ks], sa[ni], 0, 0, 0);
    const int qrow = rbase + lm;
    if (k0 + 63 > rbase) { // diagonal tile: causal mask
#pragma unroll
      for (int ni = 0; ni < 4; ni++)
#pragma unroll
        for (int r = 0; r < 4; r++)
          if (k0 + ni * 16 + quad * 4 + r > qrow) sa[ni][r] = -1e9f;
    }
    float tsum = 0.f;
#pragma unroll
    for (int ni = 0; ni < 4; ni++) {
      const float p0 = exp2f(sa[ni][0]);
      const float p1 = exp2f(sa[ni][1]);
      const float p2 = exp2f(sa[ni][2]);
      const float p3 = exp2f(sa[ni][3]);
      tsum += (p0 + p1) + (p2 + p3);
      uint2 o; o.x = f2b2t(p0, p1); o.y = f2b2t(p2, p3); // 1 v_perm each
      *(uint2*)(myP + lm * 72 + ni * 16 + quad * 4) = o;
    }
    lacc += tsum;
    // PV: B-frag = P[lm][kc*32+quad*8 ..+7] (same-wave LDS round trip)
#pragma unroll
    for (int kc = 0; kc < 2; kc++) {
      const short8 bp = *(const short8*)(myP + lm * 72 + kc * 32 + quad * 8);
#pragma unroll
      for (int dni = 0; dni < 4; dni++) {
        const int row = dni * 16 + lm;
        const int cc = (kc * 4 + quad) ^ (row & 7);
        const short8 vfr = *(const short8*)(Vc + row * 64 + cc * 8);
        ctx[dni] = __builtin_amdgcn_mfma_f32_16x16x32_bf16(vfr, bp, ctx[dni], 0, 0, 0);
      }
    }
  }
  // l reduction (cross-quad; qrow fixed per lane)
  float l = lacc;
  l += __shfl_xor(l, 16);
  l += __shfl_xor(l, 32);
  if (half < 0) { // single chunk: finalize
    const float inv = 1.0f / l;
    const int s = rbase + lm;
    const long base = (long)(b * SEQ + s) * DM + h * 64;
#pragma unroll
    for (int dni = 0; dni < 4; dni++) {
      uint2 o;
      o.x = f2b2(ctx[dni][0] * inv, ctx[dni][1] * inv);
      o.y = f2b2(ctx[dni][2] * inv, ctx[dni][3] * inv);
      *(uint2*)(O + base + dni * 16 + quad * 4) = o;
    }
  } else { // partial: raw fp32 ctx + l
    const long pt = ((long)(hb * 16 + (qt - 16))) * 2 + half;
    float* po = part + pt * 4096 + (w * 16 + lm) * 64;
#pragma unroll
    for (int dni = 0; dni < 4; dni++)
      *(float4*)(po + dni * 16 + quad * 4) =
          make_float4(ctx[dni][0], ctx[dni][1], ctx[dni][2], ctx[dni][3]);
    if (quad == 0) lpart[pt * 64 + w * 16 + lm] = l;
  }
}

// ---------- attention partial combine: out = (p0+p1)/(l0+l1) ----------
__global__ __launch_bounds__(256) void attn_combine(const float* __restrict__ part,
                                                    const float* __restrict__ lpart,
                                                    u16* __restrict__ O) {
  const int g = blockIdx.x; // 512: hb 0..31 x qtr 0..15
  const int hb = g >> 4, qtr = g & 15;
  const int h = hb & 15, b = hb >> 4;
  const int qt = 16 + qtr;
  const long pt0 = ((long)(hb * 16 + qtr)) * 2;
  const float* p0 = part + pt0 * 4096;
  const float* p1 = p0 + 4096;
  const float* lp = lpart + pt0 * 64;
  const int tid = threadIdx.x;
  const int row = tid >> 2, d0 = (tid & 3) * 16;
  const float inv = 1.0f / (lp[row] + lp[64 + row]);
  const long off = (long)(b * SEQ + qt * 64 + row) * DM + h * 64 + d0;
  u32 o[8];
#pragma unroll
  for (int i = 0; i < 4; i++) {
    const float4 a = *(const float4*)(p0 + row * 64 + d0 + i * 4);
    const float4 c = *(const float4*)(p1 + row * 64 + d0 + i * 4);
    o[i * 2 + 0] = f2b2((a.x + c.x) * inv, (a.y + c.y) * inv);
    o[i * 2 + 1] = f2b2((a.z + c.z) * inv, (a.w + c.w) * inv);
  }
  *(uint4*)(O + off) = make_uint4(o[0], o[1], o[2], o[3]);
  *(uint4*)(O + off + 8) = make_uint4(o[4], o[5], o[6], o[7]);
}

// ---------- layernorm (input already has bias+residual folded), one barrier ----------
template <bool WB>
__global__ __launch_bounds__(256) void ln_k(const float* __restrict__ in,
                                            const float* __restrict__ gam,
                                            const float* __restrict__ bet,
                                            float* __restrict__ outF,
                                            u16* __restrict__ outB) {
  __shared__ float red[8];
  const int row = blockIdx.x, tid = threadIdx.x;
  const long off = (long)row * DM;
  const float4 v = ((const float4*)(in + off))[tid];
  float s1 = v.x + v.y + v.z + v.w;
  float s2 = v.x * v.x + v.y * v.y + v.z * v.z + v.w * v.w;
  s1 += __shfl_xor(s1, 1); s2 += __shfl_xor(s2, 1);
  s1 += __shfl_xor(s1, 2); s2 += __shfl_xor(s2, 2);
  s1 += __shfl_xor(s1, 4); s2 += __shfl_xor(s2, 4);
  s1 += __shfl_xor(s1, 8); s2 += __shfl_xor(s2, 8);
  s1 += __shfl_xor(s1, 16); s2 += __shfl_xor(s2, 16);
  s1 += __shfl_xor(s1, 32); s2 += __shfl_xor(s2, 32);
  if ((tid & 63) == 0) { red[tid >> 6] = s1; red[4 + (tid >> 6)] = s2; }
  __syncthreads();
  const float mean = (red[0] + red[1] + red[2] + red[3]) * (1.f / DM);
  const float ex2 = (red[4] + red[5] + red[6] + red[7]) * (1.f / DM);
  const float var = fmaxf(ex2 - mean * mean, 0.f);
  const float rs = rsqrtf(var + 1e-6f);
  const float4 g4 = ((const float4*)gam)[tid];
  const float4 be4 = ((const float4*)bet)[tid];
  const float o0 = (v.x - mean) * rs * g4.x + be4.x;
  const float o1 = (v.y - mean) * rs * g4.y + be4.y;
  const float o2 = (v.z - mean) * rs * g4.z + be4.z;
  const float o3 = (v.w - mean) * rs * g4.w + be4.w;
  ((float4*)(outF + off))[tid] = make_float4(o0, o1, o2, o3);
  if constexpr (WB) {
    uint2 o; o.x = f2b2(o0, o1); o.y = f2b2(o2, o3);
    ((uint2*)(outB + off))[tid] = o;
  }
}

// ---------- launcher ----------
extern "C" void kernel_launch(void* const* d_in, const int* in_sizes, int n_in,
                              void* d_out, int out_size, void* d_ws, size_t ws_size,
                              hipStream_t stream) {
  (void)in_sizes; (void)n_in; (void)out_size; (void)ws_size;
  const float* x = (const float*)d_in[0];
  const float* wq = (const float*)d_in[2];
  const float* bq = (const float*)d_in[3];
  const float* wk = (const float*)d_in[4];
  const float* bk = (const float*)d_in[5];
  const float* wv = (const float*)d_in[6];
  const float* bv = (const float*)d_in[7];
  const float* wo = (const float*)d_in[8];
  const float* bo = (const float*)d_in[9];
  const float* g1 = (const float*)d_in[10];
  const float* be1 = (const float*)d_in[11];
  const float* w1 = (const float*)d_in[12];
  const float* b1 = (const float*)d_in[13];
  const float* w2 = (const float*)d_in[14];
  const float* b2 = (const float*)d_in[15];
  const float* g2 = (const float*)d_in[16];
  const float* be2 = (const float*)d_in[17];
  float* out = (float*)d_out;
  uint8_t* ws = (uint8_t*)d_ws;
  const size_t MB = 1024ull * 1024ull;
  u16* wot = (u16*)(ws + 0 * MB);    // 2MB
  u16* w1t = (u16*)(ws + 2 * MB);    // 8MB
  u16* w2t = (u16*)(ws + 10 * MB);   // 8MB
  u16* btq = (u16*)(ws + 18 * MB);   // 6MB
  u16* xb  = (u16*)(ws + 24 * MB);   // 8MB
  u16* qb  = (u16*)(ws + 32 * MB);   // 8MB [B,H,S,64]
  u16* kb  = (u16*)(ws + 40 * MB);   // 8MB
  u16* vt  = (u16*)(ws + 48 * MB);   // 8MB [B,H,64,S] (written by QKV epilogue)
  u16* ctxb = (u16*)(ws + 56 * MB);  // 8MB [B,S,DM]
  float* apart = (float*)(ws + 64 * MB); // attn ctx partials 16.8MB
  float* lpart = (float*)(ws + 81 * MB); // attn l partials 256KB
  float* res1 = (float*)(ws + 88 * MB);  // 16MB fp32 (Wo out, bias+resid folded)
  u16* o1b = (u16*)(ws + 104 * MB);  // 8MB
  float* o1f = (float*)(ws + 112 * MB); // 16MB (peak 128MB)
  u16* h1 = (u16*)(ws + 18 * MB);    // 32MB, aliases btq/xb/qb/kb/vt (dead by FFN1)
  float* res2 = (float*)(ws + 88 * MB); // aliases res1 (dead after LN1)

  prep_k<<<dim3(16384), dim3(256), 0, stream>>>(x, wq, wk, wv, wo, w1, w2, xb, btq, wot,
                                                w1t, w2t);

  gemm_bt<EPI_QKV><<<dim3(24, 32), dim3(256), 0, stream>>>(
      xb, btq, MROWS, 3072, 1024, bq, bk, bv, nullptr, nullptr, nullptr, qb, kb, vt);

  attn_fused<<<dim3(1536), dim3(256), 0, stream>>>(qb, kb, vt, ctxb, apart, lpart);
  attn_combine<<<dim3(512), dim3(256), 0, stream>>>(apart, lpart, ctxb);

  gemm_bt<EPI_ADDRES><<<dim3(8, 32), dim3(256), 0, stream>>>(
      ctxb, wot, MROWS, 1024, 1024, bo, nullptr, nullptr, x, res1, nullptr, nullptr,
      nullptr, nullptr);

  ln_k<true><<<dim3(4096), dim3(256), 0, stream>>>(res1, g1, be1, o1f, o1b);

  gemm_bt<EPI_RELUB><<<dim3(32, 32), dim3(256), 0, stream>>>(
      o1b, w1t, MROWS, 4096, 1024, b1, nullptr, nullptr, nullptr, nullptr, h1, nullptr,
      nullptr, nullptr);

  gemm_bt<EPI_ADDRES><<<dim3(8, 32), dim3(256), 0, stream>>>(
      h1, w2t, MROWS, 1024, 4096, b2, nullptr, nullptr, o1f, res2, nullptr, nullptr,
      nullptr, nullptr);

  ln_k<false><<<dim3(4096), dim3(256), 0, stream>>>(res2, g2, be2, out, nullptr);
}

// Round 7
// 346.798 us; speedup vs baseline: 1.0376x; 1.0376x over previous
//
#include <hip/hip_runtime.h>
#include <stdint.h>

typedef unsigned short u16;
typedef unsigned int u32;
typedef __attribute__((ext_vector_type(8))) short short8;
typedef __attribute__((ext_vector_type(4))) float f32x4;

#define NHEADS 16
#define SEQ 2048
#define DM 1024
#define MROWS 4096 // B*S
#define FF 4096

static_assert(sizeof(short8) == 16, "short8 must be 16B");

// ---------- helpers ----------
__device__ __forceinline__ u16 f2b(float f) {
  u32 u = __float_as_uint(f);
  u += 0x7fffu + ((u >> 16) & 1u); // RNE
  return (u16)(u >> 16);
}
__device__ __forceinline__ u32 f2b2(float lo, float hi) {
  u32 a = __float_as_uint(lo); a += 0x7fffu + ((a >> 16) & 1u);
  u32 b = __float_as_uint(hi); b += 0x7fffu + ((b >> 16) & 1u);
  return (a >> 16) | (b & 0xffff0000u);
}
// truncating pack (1 v_perm_b32): [lo.hi16 | hi.hi16]
__device__ __forceinline__ u32 f2b2t(float lo, float hi) {
  return __builtin_amdgcn_perm(__float_as_uint(hi), __float_as_uint(lo), 0x07060302u);
}
__device__ __forceinline__ float b2f(u16 h) { return __uint_as_float(((u32)h) << 16); }

__device__ __forceinline__ void async_cp16(const u16* g, u16* l) {
  __builtin_amdgcn_global_load_lds((const __attribute__((address_space(1))) void*)g,
                                   (__attribute__((address_space(3))) void*)l, 16, 0, 0);
}

// ---------- fused prep: cvt x -> bf16, transpose all weights -> bf16 [N,K] ----------
__global__ __launch_bounds__(256) void prep_k(const float* __restrict__ x,
                                              const float* __restrict__ wq,
                                              const float* __restrict__ wk,
                                              const float* __restrict__ wv,
                                              const float* __restrict__ wo,
                                              const float* __restrict__ w1,
                                              const float* __restrict__ w2,
                                              u16* __restrict__ xb, u16* __restrict__ btq,
                                              u16* __restrict__ wot, u16* __restrict__ w1t,
                                              u16* __restrict__ w2t) {
  const int bid = blockIdx.x, tid = threadIdx.x;
  if (bid < 4096) { // cvt x (4M floats, 1 float4/thread)
    const int i = bid * 256 + tid;
    const float4 v = ((const float4*)x)[i];
    uint2 o; o.x = f2b2(v.x, v.y); o.y = f2b2(v.z, v.w);
    ((uint2*)xb)[i] = o;
    return;
  }
  __shared__ float tile[32][33];
  const int tb = bid - 4096;
  const float* in; u16* out; int N, K, n0, k0;
  if (tb < 4096) {
    const int m = tb >> 10, t = tb & 1023;
    if (m == 0) { in = wq; out = btq; }
    else if (m == 1) { in = wk; out = btq + 1024 * 1024; }
    else if (m == 2) { in = wv; out = btq + 2 * 1024 * 1024; }
    else { in = wo; out = wot; }
    N = 1024; K = 1024; n0 = (t & 31) * 32; k0 = (t >> 5) * 32;
  } else if (tb < 8192) {
    const int t = tb - 4096;
    in = w1; out = w1t; N = 4096; K = 1024; n0 = (t & 127) * 32; k0 = (t >> 7) * 32;
  } else {
    const int t = tb - 8192;
    in = w2; out = w2t; N = 1024; K = 4096; n0 = (t & 31) * 32; k0 = (t >> 5) * 32;
  }
  const int tx = tid & 31, ty = tid >> 5;
#pragma unroll
  for (int i = 0; i < 4; i++) {
    const int r = ty + i * 8;
    tile[r][tx] = in[(long)(k0 + r) * N + n0 + tx];
  }
  __syncthreads();
#pragma unroll
  for (int i = 0; i < 4; i++) {
    const int r = ty + i * 8;
    out[(long)(n0 + r) * K + k0 + tx] = f2b(tile[tx][r]);
  }
}

// ---------- GEMM C = A @ Bt^T  (A:[M,LDA] bf16, Bt:[N,LDA] bf16) ----------
// KITER = k-length per pass; KOFF = per-blockIdx.z k offset (split-K).
// XCD-aware tile decode: lid%8 = XCD (round-robin dispatch assumption); XCD j
// owns tm-tiles {4j..4j+3} x all tn -> per-XCD A working set <= 4MB (fits L2).
// Requires gridDim.y == 32.
#define BM 128
#define BN 128
#define BK 64
#define EPI_QKV 0
#define EPI_RELUB 2
#define EPI_PART 3

template <int EPI>
__global__ __launch_bounds__(256, 2) void gemm_bt(
    const u16* __restrict__ A, const u16* __restrict__ Bt, const int M, const int N,
    const int KITER, const int LDA, const int KOFF,
    const float* __restrict__ bias0, const float* __restrict__ bias1,
    const float* __restrict__ bias2,
    float* __restrict__ outF, u16* __restrict__ outB, u16* __restrict__ outQ,
    u16* __restrict__ outK, u16* __restrict__ outV) {
  __shared__ u16 As[BM * BK];
  __shared__ u16 Bs[BN * BK];
  const int tid = threadIdx.x;
  const int lane = tid & 63;
  const int wv = tid >> 6;
  const int quad = lane >> 4;
  const int lm = lane & 15;
  // swizzled tile decode
  const int lid = blockIdx.y * gridDim.x + blockIdx.x;
  const int s = lid >> 3;
  const int tm = ((lid & 7) * 4 + (s & 3)) * BM;
  const int tn = (s >> 2) * BN;
  const int wr = (wv >> 1) * 64;
  const int wc = (wv & 1) * 64;
  const int wslotbase = tid & ~63;
  const long zoff = (long)blockIdx.z * KOFF;
  const u16* Ap = A + zoff;
  const u16* Btp = Bt + zoff;

  const f32x4 z4 = {0.f, 0.f, 0.f, 0.f};
  f32x4 acc[4][4];
#pragma unroll
  for (int i = 0; i < 4; i++)
#pragma unroll
    for (int j = 0; j < 4; j++) acc[i][j] = z4;

  for (int kk = 0; kk < KITER; kk += BK) {
    __syncthreads();
#pragma unroll
    for (int t = 0; t < 4; t++) {
      const int slot = t * 256 + tid;
      const int row = slot >> 3;
      const int c = (slot & 7) ^ (row & 7);
      async_cp16(Ap + (long)(tm + row) * LDA + kk + c * 8,
                 As + (long)(t * 256 + wslotbase) * 8);
    }
#pragma unroll
    for (int t = 0; t < 4; t++) {
      const int slot = t * 256 + tid;
      const int row = slot >> 3;
      const int c = (slot & 7) ^ (row & 7);
      async_cp16(Btp + (long)(tn + row) * LDA + kk + c * 8,
                 Bs + (long)(t * 256 + wslotbase) * 8);
    }
    __syncthreads();
#pragma unroll
    for (int ks = 0; ks < 2; ks++) {
      short8 af[4], bf[4];
#pragma unroll
      for (int mi = 0; mi < 4; mi++) {
        const int row = wr + mi * 16 + lm;
        const int cc = (4 * ks + quad) ^ (row & 7);
        af[mi] = *(const short8*)(As + row * 64 + cc * 8);
      }
#pragma unroll
      for (int ni = 0; ni < 4; ni++) {
        const int row = wc + ni * 16 + lm;
        const int cc = (4 * ks + quad) ^ (row & 7);
        bf[ni] = *(const short8*)(Bs + row * 64 + cc * 8);
      }
#pragma unroll
      for (int mi = 0; mi < 4; mi++)
#pragma unroll
        for (int ni = 0; ni < 4; ni++)
          acc[mi][ni] =
              __builtin_amdgcn_mfma_f32_16x16x32_bf16(af[mi], bf[ni], acc[mi][ni], 0, 0, 0);
    }
  }

  if constexpr (EPI == EPI_QKV) {
    const int which = tn >> 10; // 0=q,1=k,2=v (block-uniform)
    const int bb = tm >> 11;
    if (which < 2) {
      const float* bs = which == 0 ? bias0 : bias1;
      u16* os = which == 0 ? outQ : outK;
      // q pre-scale: 1/sqrt(64) * log2(e) folded in -> attn uses exp2 directly
      const float scale = which == 0 ? 0.125f * 1.44269504f : 1.0f;
#pragma unroll
      for (int ni = 0; ni < 4; ni++) {
        const int n = tn + wc + ni * 16 + lm;
        const int hd = n & 1023;
        const int h = hd >> 6, dep = hd & 63;
        const float bval = bs[hd];
#pragma unroll
        for (int mi = 0; mi < 4; mi++) {
#pragma unroll
          for (int r = 0; r < 4; r++) {
            const int ss = (tm & 2047) + wr + mi * 16 + quad * 4 + r;
            os[(((long)(bb * NHEADS + h) * SEQ + ss) << 6) + dep] =
                f2b((acc[mi][ni][r] + bval) * scale);
          }
        }
      }
    } else { // V: write transposed [B,H,64,S] directly (8B stores per lane)
#pragma unroll
      for (int ni = 0; ni < 4; ni++) {
        const int n = tn + wc + ni * 16 + lm;
        const int hd = n & 1023;
        const int h = hd >> 6, dep = hd & 63;
        const float bval = bias2[hd];
        u16* vrow = outV + ((long)(bb * NHEADS + h) * 64 + dep) * SEQ;
#pragma unroll
        for (int mi = 0; mi < 4; mi++) {
          const int ss = (tm & 2047) + wr + mi * 16 + quad * 4;
          uint2 o;
          o.x = f2b2(acc[mi][ni][0] + bval, acc[mi][ni][1] + bval);
          o.y = f2b2(acc[mi][ni][2] + bval, acc[mi][ni][3] + bval);
          *(uint2*)(vrow + ss) = o;
        }
      }
    }
  } else if constexpr (EPI == EPI_PART) {
    float* po = outF + (long)blockIdx.z * M * N;
#pragma unroll
    for (int mi = 0; mi < 4; mi++) {
#pragma unroll
      for (int r = 0; r < 4; r++) {
        const int m = tm + wr + mi * 16 + quad * 4 + r;
        const long rowo = (long)m * N;
#pragma unroll
        for (int ni = 0; ni < 4; ni++) {
          const int n = tn + wc + ni * 16 + lm;
          po[rowo + n] = acc[mi][ni][r];
        }
      }
    }
  } else { // EPI_RELUB
#pragma unroll
    for (int mi = 0; mi < 4; mi++) {
#pragma unroll
      for (int r = 0; r < 4; r++) {
        const int m = tm + wr + mi * 16 + quad * 4 + r;
        const long rowo = (long)m * N;
#pragma unroll
        for (int ni = 0; ni < 4; ni++) {
          const int n = tn + wc + ni * 16 + lm;
          const float v = acc[mi][ni][r] + bias0[n];
          outB[rowo + n] = f2b(fmaxf(v, 0.f));
        }
      }
    }
  }
}

// ---------- fused causal attention, k-split with exact-softmax partials ----------
// Q,K: [B,H,S,64] bf16 (q pre-scaled by 0.125*log2e); Vt: [B,H,64,S]; O: [B,S,DM].
// No online max (scores bounded, exp2 exact) => flash partials combine by PLAIN
// SUMMATION. Block = 256 thr / 4 waves / one 64-row q-tile; wave owns 16 rows.
// qt < 16: single block, full k-range, final bf16. qt >= 16: two blocks, half
// k-range each, fp32 ctx partial + l; combine kernel sums. P packed to bf16 via
// v_perm (truncation). K/V double-buffered; staging geometry hoisted.
__global__ __launch_bounds__(256, 3) void attn_fused(const u16* __restrict__ Q,
                                                     const u16* __restrict__ K,
                                                     const u16* __restrict__ Vt,
                                                     u16* __restrict__ O,
                                                     float* __restrict__ part,
                                                     float* __restrict__ lpart) {
  __shared__ u16 Ks[2][64 * 64];
  __shared__ u16 Vs[2][64 * 64];
  __shared__ u16 Ps[4][16 * 72];
  const int tid = threadIdx.x;
  const int lane = tid & 63, w = tid >> 6, quad = lane >> 4, lm = lane & 15;
  const int bid = blockIdx.x;
  const int idx = bid >> 5, hb = bid & 31;
  const int h = hb & 15, b = hb >> 4;
  int qt, c0, nkl, half;
  if (idx < 32) { // halves of qt 16..31 (dispatched first: longest work)
    qt = 16 + (idx >> 1);
    const int nk = qt + 1;
    const int h0 = (nk + 1) >> 1;
    half = idx & 1;
    if (half == 0) { c0 = 0; nkl = h0; } else { c0 = h0; nkl = nk - h0; }
  } else { // singles qt 15..0
    qt = 47 - idx; c0 = 0; nkl = qt + 1; half = -1;
  }
  const long bh = (long)(b * NHEADS + h);
  const u16* Qb = Q + bh * SEQ * 64;
  const u16* Kb = K + bh * SEQ * 64;
  const u16* Vb = Vt + bh * (long)64 * SEQ;
  const int rbase = qt * 64 + w * 16; // wave's 16 q-rows
  const int wslot = tid & ~63;

  // hoisted per-thread staging geometry (2 16B slots per thread per buffer)
  long kgo[2], vgo[2];
  int ldso[2];
#pragma unroll
  for (int i = 0; i < 2; i++) {
    const int slot = i * 256 + tid;
    const int row = slot >> 3;
    const int cg = (slot & 7) ^ (row & 7);
    kgo[i] = (long)row * 64 + cg * 8;
    vgo[i] = (long)row * SEQ + cg * 8;
    ldso[i] = (i * 256 + wslot) * 8;
  }

  // Q frag (B-operand): lane holds Q[rbase+lm][ks*32+quad*8 ..+7]
  short8 qf[2];
#pragma unroll
  for (int ks = 0; ks < 2; ks++)
    qf[ks] = *(const short8*)(Qb + (long)(rbase + lm) * 64 + ks * 32 + quad * 8);

  const f32x4 z4 = {0.f, 0.f, 0.f, 0.f};
  f32x4 ctx[4];
#pragma unroll
  for (int d = 0; d < 4; d++) ctx[d] = z4;
  float lacc = 0.f;
  u16* myP = (u16*)Ps[w];

  { // prologue: stage tile c0 into buffer 0
    const long ko = (long)c0 * 64 * 64;
#pragma unroll
    for (int i = 0; i < 2; i++) {
      async_cp16(Kb + ko + kgo[i], Ks[0] + ldso[i]);
      async_cp16(Vb + c0 * 64 + vgo[i], Vs[0] + ldso[i]);
    }
  }

  for (int t = 0; t < nkl; t++) {
    const int cur = t & 1;
    const int k0 = (c0 + t) * 64;
    __syncthreads(); // buf[cur] DMA drained (prefetched a full phase ago)
    if (t + 1 < nkl) {
      const long ko = (long)(k0 + 64) * 64;
#pragma unroll
      for (int i = 0; i < 2; i++) {
        async_cp16(Kb + ko + kgo[i], Ks[1 - cur] + ldso[i]);
        async_cp16(Vb + (k0 + 64) + vgo[i], Vs[1 - cur] + ldso[i]);
      }
    }
    const u16* Kc = Ks[cur];
    const u16* Vc = Vs[cur];
    short8 kf[4][2]; // A-operand: K[k0+ni*16+lm][ks*32+quad*8 ..+7]
#pragma unroll
    for (int ni = 0; ni < 4; ni++) {
      const int row = ni * 16 + lm;
      const int r8 = row & 7;
#pragma unroll
      for (int ks = 0; ks < 2; ks++) {
        const int cc = (ks * 4 + quad) ^ r8;
        kf[ni][ks] = *(const short8*)(Kc + row * 64 + cc * 8);
      }
    }
    f32x4 sa[4]; // S^T: lane holds key=k0+ni*16+quad*4+r, qrow=rbase+lm
#pragma unroll
    for (int i = 0; i < 4; i++) sa[i] = z4;
#pragma unroll
    for (int ks = 0; ks < 2; ks++)
#pragma unroll
      for (int ni = 0; ni < 4; ni++)
        sa[ni] = __builtin_amdgcn_mfma_f32_16x16x32_bf16(kf[ni][ks], qf[ks], sa[ni], 0, 0, 0);
    const int qrow = rbase + lm;
    if (k0 + 63 > rbase) { // diagonal tile: causal mask
#pragma unroll
      for (int ni = 0; ni < 4; ni++)
#pragma unroll
        for (int r = 0; r < 4; r++)
          if (k0 + ni * 16 + quad * 4 + r > qrow) sa[ni][r] = -1e9f;
    }
    float tsum = 0.f;
#pragma unroll
    for (int ni = 0; ni < 4; ni++) {
      const float p0 = exp2f(sa[ni][0]);
      const float p1 = exp2f(sa[ni][1]);
      const float p2 = exp2f(sa[ni][2]);
      const float p3 = exp2f(sa[ni][3]);
      tsum += (p0 + p1) + (p2 + p3);
      uint2 o; o.x = f2b2t(p0, p1); o.y = f2b2t(p2, p3); // 1 v_perm each
      *(uint2*)(myP + lm * 72 + ni * 16 + quad * 4) = o;
    }
    lacc += tsum;
    // PV: B-frag = P[lm][kc*32+quad*8 ..+7] (same-wave LDS round trip)
#pragma unroll
    for (int kc = 0; kc < 2; kc++) {
      const short8 bp = *(const short8*)(myP + lm * 72 + kc * 32 + quad * 8);
#pragma unroll
      for (int dni = 0; dni < 4; dni++) {
        const int row = dni * 16 + lm;
        const int cc = (kc * 4 + quad) ^ (row & 7);
        const short8 vfr = *(const short8*)(Vc + row * 64 + cc * 8);
        ctx[dni] = __builtin_amdgcn_mfma_f32_16x16x32_bf16(vfr, bp, ctx[dni], 0, 0, 0);
      }
    }
  }
  // l reduction (cross-quad; qrow fixed per lane)
  float l = lacc;
  l += __shfl_xor(l, 16);
  l += __shfl_xor(l, 32);
  if (half < 0) { // single chunk: finalize
    const float inv = 1.0f / l;
    const int s = rbase + lm;
    const long base = (long)(b * SEQ + s) * DM + h * 64;
#pragma unroll
    for (int dni = 0; dni < 4; dni++) {
      uint2 o;
      o.x = f2b2(ctx[dni][0] * inv, ctx[dni][1] * inv);
      o.y = f2b2(ctx[dni][2] * inv, ctx[dni][3] * inv);
      *(uint2*)(O + base + dni * 16 + quad * 4) = o;
    }
  } else { // partial: raw fp32 ctx + l
    const long pt = ((long)(hb * 16 + (qt - 16))) * 2 + half;
    float* po = part + pt * 4096 + (w * 16 + lm) * 64;
#pragma unroll
    for (int dni = 0; dni < 4; dni++)
      *(float4*)(po + dni * 16 + quad * 4) =
          make_float4(ctx[dni][0], ctx[dni][1], ctx[dni][2], ctx[dni][3]);
    if (quad == 0) lpart[pt * 64 + w * 16 + lm] = l;
  }
}

// ---------- attention partial combine: out = (p0+p1)/(l0+l1) ----------
__global__ __launch_bounds__(256) void attn_combine(const float* __restrict__ part,
                                                    const float* __restrict__ lpart,
                                                    u16* __restrict__ O) {
  const int g = blockIdx.x; // 512: hb 0..31 x qtr 0..15
  const int hb = g >> 4, qtr = g & 15;
  const int h = hb & 15, b = hb >> 4;
  const int qt = 16 + qtr;
  const long pt0 = ((long)(hb * 16 + qtr)) * 2;
  const float* p0 = part + pt0 * 4096;
  const float* p1 = p0 + 4096;
  const float* lp = lpart + pt0 * 64;
  const int tid = threadIdx.x;
  const int row = tid >> 2, d0 = (tid & 3) * 16;
  const float inv = 1.0f / (lp[row] + lp[64 + row]);
  const long off = (long)(b * SEQ + qt * 64 + row) * DM + h * 64 + d0;
  u32 o[8];
#pragma unroll
  for (int i = 0; i < 4; i++) {
    const float4 a = *(const float4*)(p0 + row * 64 + d0 + i * 4);
    const float4 c = *(const float4*)(p1 + row * 64 + d0 + i * 4);
    o[i * 2 + 0] = f2b2((a.x + c.x) * inv, (a.y + c.y) * inv);
    o[i * 2 + 1] = f2b2((a.z + c.z) * inv, (a.w + c.w) * inv);
  }
  *(uint4*)(O + off) = make_uint4(o[0], o[1], o[2], o[3]);
  *(uint4*)(O + off + 8) = make_uint4(o[4], o[5], o[6], o[7]);
}

// ---------- fused split-K combine + residual + bias + layernorm (one barrier) ----------
template <bool WB>
__global__ __launch_bounds__(256) void layernorm2_k(const float* __restrict__ p0,
                                                    const float* __restrict__ p1,
                                                    const float* __restrict__ resid,
                                                    const float* __restrict__ bias,
                                                    const float* __restrict__ gam,
                                                    const float* __restrict__ bet,
                                                    float* __restrict__ outF,
                                                    u16* __restrict__ outB) {
  __shared__ float red[8];
  const int row = blockIdx.x, tid = threadIdx.x;
  const long off = (long)row * DM;
  const float4 a4 = ((const float4*)(p0 + off))[tid];
  const float4 b4v = ((const float4*)(p1 + off))[tid];
  const float4 r4 = ((const float4*)(resid + off))[tid];
  const float4 bi4 = ((const float4*)bias)[tid];
  float4 v;
  v.x = a4.x + b4v.x + r4.x + bi4.x;
  v.y = a4.y + b4v.y + r4.y + bi4.y;
  v.z = a4.z + b4v.z + r4.z + bi4.z;
  v.w = a4.w + b4v.w + r4.w + bi4.w;
  float s1 = v.x + v.y + v.z + v.w;
  float s2 = v.x * v.x + v.y * v.y + v.z * v.z + v.w * v.w;
  s1 += __shfl_xor(s1, 1); s2 += __shfl_xor(s2, 1);
  s1 += __shfl_xor(s1, 2); s2 += __shfl_xor(s2, 2);
  s1 += __shfl_xor(s1, 4); s2 += __shfl_xor(s2, 4);
  s1 += __shfl_xor(s1, 8); s2 += __shfl_xor(s2, 8);
  s1 += __shfl_xor(s1, 16); s2 += __shfl_xor(s2, 16);
  s1 += __shfl_xor(s1, 32); s2 += __shfl_xor(s2, 32);
  if ((tid & 63) == 0) { red[tid >> 6] = s1; red[4 + (tid >> 6)] = s2; }
  __syncthreads();
  const float mean = (red[0] + red[1] + red[2] + red[3]) * (1.f / DM);
  const float ex2 = (red[4] + red[5] + red[6] + red[7]) * (1.f / DM);
  const float var = fmaxf(ex2 - mean * mean, 0.f);
  const float rs = rsqrtf(var + 1e-6f);
  const float4 g4 = ((const float4*)gam)[tid];
  const float4 be4 = ((const float4*)bet)[tid];
  const float o0 = (v.x - mean) * rs * g4.x + be4.x;
  const float o1 = (v.y - mean) * rs * g4.y + be4.y;
  const float o2 = (v.z - mean) * rs * g4.z + be4.z;
  const float o3 = (v.w - mean) * rs * g4.w + be4.w;
  ((float4*)(outF + off))[tid] = make_float4(o0, o1, o2, o3);
  if constexpr (WB) {
    uint2 o; o.x = f2b2(o0, o1); o.y = f2b2(o2, o3);
    ((uint2*)(outB + off))[tid] = o;
  }
}

// ---------- launcher ----------
extern "C" void kernel_launch(void* const* d_in, const int* in_sizes, int n_in,
                              void* d_out, int out_size, void* d_ws, size_t ws_size,
                              hipStream_t stream) {
  (void)in_sizes; (void)n_in; (void)out_size; (void)ws_size;
  const float* x = (const float*)d_in[0];
  const float* wq = (const float*)d_in[2];
  const float* bq = (const float*)d_in[3];
  const float* wk = (const float*)d_in[4];
  const float* bk = (const float*)d_in[5];
  const float* wv = (const float*)d_in[6];
  const float* bv = (const float*)d_in[7];
  const float* wo = (const float*)d_in[8];
  const float* bo = (const float*)d_in[9];
  const float* g1 = (const float*)d_in[10];
  const float* be1 = (const float*)d_in[11];
  const float* w1 = (const float*)d_in[12];
  const float* b1 = (const float*)d_in[13];
  const float* w2 = (const float*)d_in[14];
  const float* b2 = (const float*)d_in[15];
  const float* g2 = (const float*)d_in[16];
  const float* be2 = (const float*)d_in[17];
  float* out = (float*)d_out;
  uint8_t* ws = (uint8_t*)d_ws;
  const size_t MB = 1024ull * 1024ull;
  u16* wot = (u16*)(ws + 0 * MB);    // 2MB
  u16* w1t = (u16*)(ws + 2 * MB);    // 8MB
  u16* w2t = (u16*)(ws + 10 * MB);   // 8MB
  u16* btq = (u16*)(ws + 18 * MB);   // 6MB
  u16* xb  = (u16*)(ws + 24 * MB);   // 8MB
  u16* qb  = (u16*)(ws + 32 * MB);   // 8MB [B,H,S,64]
  u16* kb  = (u16*)(ws + 40 * MB);   // 8MB
  u16* vt  = (u16*)(ws + 48 * MB);   // 8MB [B,H,64,S] (written by QKV epilogue)
  u16* ctxb = (u16*)(ws + 56 * MB);  // 8MB [B,S,DM]
  float* apart = (float*)(ws + 64 * MB); // attn ctx partials 16.8MB [64,81)
  float* lpart = (float*)(ws + 81 * MB); // attn l partials 256KB
  float* part = (float*)(ws + 64 * MB);  // GEMM split-K partials 2x16MB [64,96) — aliases apart (dead)
  u16* o1b = (u16*)(ws + 96 * MB);   // 8MB
  float* o1f = (float*)(ws + 104 * MB); // 16MB (peak 120MB)
  u16* h1 = (u16*)(ws + 18 * MB);    // 32MB, aliases btq/xb/qb/kb/vt (dead by FFN1)

  prep_k<<<dim3(16384), dim3(256), 0, stream>>>(x, wq, wk, wv, wo, w1, w2, xb, btq, wot,
                                                w1t, w2t);

  gemm_bt<EPI_QKV><<<dim3(24, 32), dim3(256), 0, stream>>>(
      xb, btq, MROWS, 3072, 1024, 1024, 0, bq, bk, bv, nullptr, nullptr, qb, kb, vt);

  attn_fused<<<dim3(1536), dim3(256), 0, stream>>>(qb, kb, vt, ctxb, apart, lpart);
  attn_combine<<<dim3(512), dim3(256), 0, stream>>>(apart, lpart, ctxb);

  // Wo: split-K=2 partials (apart/lpart dead from here; part aliases them)
  gemm_bt<EPI_PART><<<dim3(8, 32, 2), dim3(256), 0, stream>>>(
      ctxb, wot, MROWS, 1024, 512, 1024, 512, nullptr, nullptr, nullptr, part, nullptr,
      nullptr, nullptr, nullptr);

  layernorm2_k<true><<<dim3(4096), dim3(256), 0, stream>>>(
      part, part + (long)MROWS * DM, x, bo, g1, be1, o1f, o1b);

  gemm_bt<EPI_RELUB><<<dim3(32, 32), dim3(256), 0, stream>>>(
      o1b, w1t, MROWS, 4096, 1024, 1024, 0, b1, nullptr, nullptr, nullptr, h1, nullptr,
      nullptr, nullptr);

  // FFN2: split-K=2 partials
  gemm_bt<EPI_PART><<<dim3(8, 32, 2), dim3(256), 0, stream>>>(
      h1, w2t, MROWS, 1024, 2048, 4096, 2048, nullptr, nullptr, nullptr, part, nullptr,
      nullptr, nullptr, nullptr);

  layernorm2_k<false><<<dim3(4096), dim3(256), 0, stream>>>(
      part, part + (long)MROWS * DM, o1f, b2, g2, be2, out, nullptr);
}